// Round 4
// baseline (389.459 us; speedup 1.0000x reference)
//
#include <hip/hip_runtime.h>
#include <cstdint>

#define EMB 1024
#define HID 2048
#define BATCH 4
#define SEQ 2048
#define MROWS (BATCH * SEQ) /* 8192 */
#define N1 (3 * HID)        /* 6144 */
#define K1 EMB              /* 1024 */
#define N2 EMB              /* 1024 */
#define K2 HID              /* 2048 */

#define NX (MROWS * EMB)  /* 8388608 */
#define NW1 (N1 * K1)     /* 6291456 */
#define NW2 (N2 * K2)     /* 2097152 */

#define SEG 32            /* time segments per (b,ch) */
#define SLEN (SEQ / SEG)  /* 64 steps per segment */

typedef unsigned short ushort_t;
typedef __bf16 bf16x8 __attribute__((ext_vector_type(8)));
typedef float f32x4 __attribute__((ext_vector_type(4)));
typedef ushort_t us4 __attribute__((ext_vector_type(4)));

__device__ __forceinline__ ushort_t f2bf(float f) {
    uint32_t u = __builtin_bit_cast(uint32_t, f);
    u += 0x7fffu + ((u >> 16) & 1u);  // round-to-nearest-even
    return (ushort_t)(u >> 16);
}
__device__ __forceinline__ float bf2f(ushort_t h) {
    uint32_t u = ((uint32_t)h) << 16;
    return __builtin_bit_cast(float, u);
}
__device__ __forceinline__ float sigm(float x) {
    return 1.f / (1.f + __expf(-x));
}

// async global->LDS, 16B per lane; LDS dest is wave-uniform base + lane*16
__device__ __forceinline__ void gload_lds16(const ushort_t* g, const ushort_t* l) {
    __builtin_amdgcn_global_load_lds(
        (const __attribute__((address_space(1))) void*)(uintptr_t)(g),
        (__attribute__((address_space(3))) void*)(uint32_t)(uintptr_t)(l),
        16, 0, 0);
}

// ---------------------------------------------------------------------------
// fp32 -> bf16 pre-convert of x, w1, w2
// ---------------------------------------------------------------------------
__global__ __launch_bounds__(256) void cvt_kernel(
    const float* __restrict__ x, const float* __restrict__ w1,
    const float* __restrict__ w2, ushort_t* __restrict__ xb,
    ushort_t* __restrict__ w1b, ushort_t* __restrict__ w2b) {
    const int i = (blockIdx.x * 256 + threadIdx.x) * 4;
    const float* s;
    ushort_t* d;
    if (i < NX) {
        s = x + i; d = xb + i;
    } else if (i < NX + NW1) {
        s = w1 + (i - NX); d = w1b + (i - NX);
    } else {
        s = w2 + (i - NX - NW1); d = w2b + (i - NX - NW1);
    }
    const float4 v = *(const float4*)s;
    us4 o;
    o.x = f2bf(v.x); o.y = f2bf(v.y); o.z = f2bf(v.z); o.w = f2bf(v.w);
    *(us4*)d = o;
}

// ---------------------------------------------------------------------------
// C = A[M,K] * B[N,K]^T  (bf16 in, fp32 acc)
// OMODE 0: C row-major fp32 [M][N].  OMODE 1: C transposed bf16 [N][M]
// (reg r = consecutive rows -> one 8-B us4 store per (i,j) fragment).
// K-loop identical to R2/R3 (bank-conflict-free swizzle, verified).
// ---------------------------------------------------------------------------
template <int OMODE>
__global__ __launch_bounds__(256) void gemm_bt(
    const ushort_t* __restrict__ A, const ushort_t* __restrict__ B,
    void* __restrict__ Cv, int M, int N, int K) {
    __shared__ ushort_t sA[128 * 32];
    __shared__ ushort_t sB[128 * 32];

    const int tid  = threadIdx.x;
    const int lane = tid & 63;
    const int wave = tid >> 6;
    const int quad = lane >> 4;
    const int l16  = lane & 15;
    const long tm0 = (long)blockIdx.y * 128;
    const long tn0 = (long)blockIdx.x * 128;
    const int wm = (wave & 1) * 64;
    const int wn = (wave >> 1) * 64;

    f32x4 acc[4][4] = {};

    const int ar0 = tid >> 2;
    const int ar1 = (tid + 256) >> 2;
    const int kq  = (tid & 3) ^ ((ar0 >> 1) & 3);
    const int ac  = kq * 8;
    const ushort_t* gA = A + (size_t)tm0 * K;
    const ushort_t* gB = B + (size_t)tn0 * K;
    ushort_t* lb0 = &sA[0] + wave * 512;
    ushort_t* lb1 = &sA[0] + 2048 + wave * 512;
    ushort_t* lb2 = &sB[0] + wave * 512;
    ushort_t* lb3 = &sB[0] + 2048 + wave * 512;

    const int rsw = (l16 >> 1) & 3;
    const int aoff = (quad ^ rsw) * 8 + l16 * 32;

    for (int k0 = 0; k0 < K; k0 += 32) {
        __syncthreads();
        gload_lds16(gA + (size_t)ar0 * K + k0 + ac, lb0);
        gload_lds16(gA + (size_t)ar1 * K + k0 + ac, lb1);
        gload_lds16(gB + (size_t)ar0 * K + k0 + ac, lb2);
        gload_lds16(gB + (size_t)ar1 * K + k0 + ac, lb3);
        __syncthreads();

        bf16x8 af[4], bfr[4];
#pragma unroll
        for (int i = 0; i < 4; ++i)
            af[i] = *(const bf16x8*)&sA[(wm + i * 16) * 32 + aoff];
#pragma unroll
        for (int j = 0; j < 4; ++j)
            bfr[j] = *(const bf16x8*)&sB[(wn + j * 16) * 32 + aoff];
#pragma unroll
        for (int i = 0; i < 4; ++i)
#pragma unroll
            for (int j = 0; j < 4; ++j)
                acc[i][j] = __builtin_amdgcn_mfma_f32_16x16x32_bf16(
                    af[i], bfr[j], acc[i][j], 0, 0, 0);
    }

    // epilogue: C/D layout col=lane&15, row=quad*4+reg
#pragma unroll
    for (int i = 0; i < 4; ++i) {
        const long row0 = tm0 + wm + i * 16 + quad * 4;
#pragma unroll
        for (int j = 0; j < 4; ++j) {
            const long col = tn0 + wn + j * 16 + l16;
            if constexpr (OMODE == 1) {
                us4 o;
                o.x = f2bf(acc[i][j][0]); o.y = f2bf(acc[i][j][1]);
                o.z = f2bf(acc[i][j][2]); o.w = f2bf(acc[i][j][3]);
                *(us4*)&((ushort_t*)Cv)[(size_t)col * M + row0] = o;
            } else {
#pragma unroll
                for (int r = 0; r < 4; ++r)
                    ((float*)Cv)[(size_t)(row0 + r) * N + col] = acc[i][j][r];
            }
        }
    }
}

// ---------------------------------------------------------------------------
// Scan over yT [6144 ch][8192 rows(b,t)] bf16 (channel-major):
//   o1T = yT + 0, zT = yT + 2048*8192, hT = yT + 4096*8192
// Each thread owns (b, ch, 64-t segment): segment = 128 B contiguous per
// stream, loaded as 8x uint4 into registers; scan runs in-register.
// Aggregates Ag/Bg/Cr laid [b][ch][SEG] (seg-contiguous for part2 float4).
// ---------------------------------------------------------------------------
__global__ __launch_bounds__(256) void scan_part1(
    const ushort_t* __restrict__ yT, const float* __restrict__ cw,
    float* __restrict__ Ag, float* __restrict__ Bg) {
    // grid: 1024 = b(4) x chgrp(256, 8ch); block: 256 = ch_l(8) x seg(32)
    const int b    = blockIdx.x >> 8;
    const int ch   = (blockIdx.x & 255) * 8 + (threadIdx.x >> 5);
    const int seg  = threadIdx.x & 31;
    const size_t pos = (size_t)b * SEQ + seg * SLEN;
    const ushort_t* zp = yT + (size_t)(2048 + ch) * MROWS + pos;
    const ushort_t* hp = yT + (size_t)(4096 + ch) * MROWS + pos;

    uint4 za[8], ha[8];
#pragma unroll
    for (int j = 0; j < 8; ++j) {
        za[j] = *(const uint4*)(zp + j * 8);
        ha[j] = *(const uint4*)(hp + j * 8);
    }
    float z1 = 0.f, z2 = 0.f, z3 = 0.f;
    if (seg) {  // conv warm-up from previous segment tail
        const uint2 w = *(const uint2*)(zp - 4);
        z3 = bf2f((ushort_t)(w.x >> 16));
        z2 = bf2f((ushort_t)(w.y & 0xffff));
        z1 = bf2f((ushort_t)(w.y >> 16));
    }
    const float w0 = cw[ch * 4 + 0], w1 = cw[ch * 4 + 1];
    const float w2 = cw[ch * 4 + 2], w3 = cw[ch * 4 + 3];

    const ushort_t* zs = (const ushort_t*)za;
    const ushort_t* hs = (const ushort_t*)ha;
    float A = 1.f, Bv = 0.f;
#pragma unroll
    for (int t = 0; t < SLEN; ++t) {
        const float zr = bf2f(zs[t]);
        const float hr = bf2f(hs[t]);
        const float cv = w0 * z3 + w1 * z2 + w2 * z1 + w3 * zr;
        const float s  = sigm(cv);
        z3 = z2; z2 = z1; z1 = zr;
        const float a = 1.f - s;
        A *= a;
        Bv = a * Bv + s * hr;
    }
    const size_t idx = ((size_t)b * HID + ch) * SEG + seg;
    Ag[idx] = A;
    Bg[idx] = Bv;
}

// one thread per (b, ch): float4-vectorized serial exclusive combine
__global__ __launch_bounds__(256) void scan_part2(
    const float* __restrict__ Ag, const float* __restrict__ Bg,
    float* __restrict__ Cr) {
    const int gid = blockIdx.x * 256 + threadIdx.x;  // [0, 8192)
    const size_t base = (size_t)gid * SEG;
    float4 a4[8], b4[8], c4[8];
#pragma unroll
    for (int j = 0; j < 8; ++j) {
        a4[j] = *(const float4*)&Ag[base + j * 4];
        b4[j] = *(const float4*)&Bg[base + j * 4];
    }
    const float* af = (const float*)a4;
    const float* bf = (const float*)b4;
    float* cf = (float*)c4;
    float carry = 0.f;
#pragma unroll
    for (int s = 0; s < SEG; ++s) {
        cf[s] = carry;
        carry = af[s] * carry + bf[s];
    }
#pragma unroll
    for (int j = 0; j < 8; ++j) *(float4*)&Cr[base + j * 4] = c4[j];
}

// replay with carry; transpose through LDS; write u row-major [8192][2048]
__global__ __launch_bounds__(256) void scan_part3(
    const ushort_t* __restrict__ yT, const float* __restrict__ cw,
    const float* __restrict__ Cr, ushort_t* __restrict__ u) {
    __shared__ ushort_t tile[256 * 68];  // [t_local][ch_local], pad 68
    // grid: 1024 = b(4) x cg(32, 64ch) x tb(8, 256t); block: tseg_l(4) x ch_l(64)
    const int b    = blockIdx.x >> 8;
    const int rem  = blockIdx.x & 255;
    const int cg   = rem >> 3;
    const int tb   = rem & 7;
    const int ch0  = cg * 64;
    const int t0b  = tb * 256;
    const int ch_l = threadIdx.x & 63;
    const int tseg = threadIdx.x >> 6;
    const int ch   = ch0 + ch_l;
    const int t0   = t0b + tseg * SLEN;
    const size_t pos = (size_t)b * SEQ + t0;
    const ushort_t* op = yT + (size_t)ch * MROWS + pos;
    const ushort_t* zp = yT + (size_t)(2048 + ch) * MROWS + pos;
    const ushort_t* hp = yT + (size_t)(4096 + ch) * MROWS + pos;

    uint4 za[8], ha[8], oa[8];
#pragma unroll
    for (int j = 0; j < 8; ++j) {
        za[j] = *(const uint4*)(zp + j * 8);
        ha[j] = *(const uint4*)(hp + j * 8);
        oa[j] = *(const uint4*)(op + j * 8);
    }
    float z1 = 0.f, z2 = 0.f, z3 = 0.f;
    if (t0) {
        const uint2 w = *(const uint2*)(zp - 4);
        z3 = bf2f((ushort_t)(w.x >> 16));
        z2 = bf2f((ushort_t)(w.y & 0xffff));
        z1 = bf2f((ushort_t)(w.y >> 16));
    }
    const float w0 = cw[ch * 4 + 0], w1 = cw[ch * 4 + 1];
    const float w2 = cw[ch * 4 + 2], w3 = cw[ch * 4 + 3];
    const int gseg = tb * 4 + tseg;
    float h = Cr[((size_t)b * HID + ch) * SEG + gseg];

    const ushort_t* zs = (const ushort_t*)za;
    const ushort_t* hs = (const ushort_t*)ha;
    const ushort_t* os = (const ushort_t*)oa;
#pragma unroll
    for (int t = 0; t < SLEN; ++t) {
        const float zr = bf2f(zs[t]);
        const float hr = bf2f(hs[t]);
        const float o1 = bf2f(os[t]);
        const float cv = w0 * z3 + w1 * z2 + w2 * z1 + w3 * zr;
        const float s  = sigm(cv);
        z3 = z2; z2 = z1; z1 = zr;
        h = (1.f - s) * h + s * hr;
        const float sil = o1 * sigm(o1);
        tile[(tseg * SLEN + t) * 68 + ch_l] = f2bf(sil * h);
    }
    __syncthreads();

    // write-out: wave w handles rows w*64+i; lanes = 64 ch -> 128-B stores
    const int wv = threadIdx.x >> 6;
    const int ln = threadIdx.x & 63;
#pragma unroll 8
    for (int i = 0; i < 64; ++i) {
        const int tr = wv * 64 + i;
        u[((size_t)b * SEQ + t0b + tr) * (size_t)HID + ch0 + ln] =
            tile[tr * 68 + ln];
    }
}

// ---------------------------------------------------------------------------
extern "C" void kernel_launch(void* const* d_in, const int* in_sizes, int n_in,
                              void* d_out, int out_size, void* d_ws, size_t ws_size,
                              hipStream_t stream) {
    const float* x  = (const float*)d_in[0];
    const float* w1 = (const float*)d_in[1];
    const float* w2 = (const float*)d_in[2];
    const float* cw = (const float*)d_in[3];
    char* ws = (char*)d_ws;

    // ws layout (bytes): xb 16MiB | w1b 12MiB | w2b 4MiB | yT 96MiB | u 32MiB
    ushort_t* xb  = (ushort_t*)(ws);
    ushort_t* w1b = (ushort_t*)(ws + (size_t)16777216);
    ushort_t* w2b = (ushort_t*)(ws + (size_t)29360128);
    ushort_t* yT  = (ushort_t*)(ws + (size_t)33554432);
    ushort_t* u   = (ushort_t*)(ws + (size_t)134217728);
    // scan scratch reuses the xb region (dead after GEMM1): 3 x 1 MiB fp32
    float* Ag = (float*)(ws);
    float* Bg = (float*)(ws + (size_t)1048576);
    float* Cr = (float*)(ws + (size_t)2097152);
    float* out = (float*)d_out;

    cvt_kernel<<<16384, 256, 0, stream>>>(x, w1, w2, xb, w1b, w2b);
    gemm_bt<1><<<dim3(N1 / 128, MROWS / 128), 256, 0, stream>>>(
        xb, w1b, (void*)yT, MROWS, N1, K1);
    scan_part1<<<1024, 256, 0, stream>>>(yT, cw, Ag, Bg);
    scan_part2<<<32, 256, 0, stream>>>(Ag, Bg, Cr);
    scan_part3<<<1024, 256, 0, stream>>>(yT, cw, Cr, u);
    gemm_bt<0><<<dim3(N2 / 128, MROWS / 128), 256, 0, stream>>>(
        u, w2b, (void*)out, MROWS, N2, K2);
}